// Round 1
// baseline (444.387 us; speedup 1.0000x reference)
//
#include <hip/hip_runtime.h>
#include <cstdint>

// SiVALinear: out[8192,4096] = x[8192,4096] @ (V^T diag(S) U^T) + bias
// Factorized bf16-MFMA path (137 GF instead of 309 GF for weight-materialize).
// GEMM structure = m97 ladder step 3: 128x128 tile, BK=32, global_load_lds w=16,
// 4 waves x 4x4 grid of v_mfma_f32_16x16x32_bf16.

#define BM 128
#define BN 128
#define BK 32

typedef __bf16 bf16x8 __attribute__((ext_vector_type(8)));
typedef float f32x4 __attribute__((ext_vector_type(4)));

__device__ __forceinline__ unsigned short f32_to_bf16(float f) {
    union { float f; uint32_t u; } v; v.f = f;
    uint32_t u = v.u;
    u += 0x7FFF + ((u >> 16) & 1);   // round-to-nearest-even
    return (unsigned short)(u >> 16);
}

// ---------- cast fp32 -> bf16, vec4 ----------
__global__ void cast_f32_bf16(const float* __restrict__ src,
                              unsigned short* __restrict__ dst, int n4) {
    int i = blockIdx.x * blockDim.x + threadIdx.x;
    if (i >= n4) return;
    float4 v = ((const float4*)src)[i];
    ushort4 o;
    o.x = f32_to_bf16(v.x); o.y = f32_to_bf16(v.y);
    o.z = f32_to_bf16(v.z); o.w = f32_to_bf16(v.w);
    ((ushort4*)dst)[i] = o;
}

// ---------- build U_cat[o, r] * S[r]  -> bf16 [4096 x 1024] row-major ----------
__global__ void build_u(const float* __restrict__ u_t, const float* __restrict__ u_d,
                        const float* __restrict__ s, unsigned short* __restrict__ ub,
                        int n4) {
    int i = blockIdx.x * blockDim.x + threadIdx.x;   // vec4 over 4096*1024
    if (i >= n4) return;
    int e = i * 4;
    int o = e >> 10;       // row (out dim)
    int r = e & 1023;      // col (rank dim), multiple of 4; 64 boundary is 4-aligned
    float4 u;
    if (r < 64) u = *(const float4*)(u_t + (size_t)o * 64 + r);
    else        u = *(const float4*)(u_d + (size_t)o * 960 + (r - 64));
    float4 sv = *(const float4*)(s + r);
    ushort4 w;
    w.x = f32_to_bf16(u.x * sv.x);
    w.y = f32_to_bf16(u.y * sv.y);
    w.z = f32_to_bf16(u.z * sv.z);
    w.w = f32_to_bf16(u.w * sv.w);
    ((ushort4*)ub)[i] = w;
}

// ---------- async global->LDS, 16B per lane ----------
__device__ __forceinline__ void stage16(const unsigned short* g, unsigned short* l) {
    __builtin_amdgcn_global_load_lds(
        (const __attribute__((address_space(1))) uint32_t*)g,
        (__attribute__((address_space(3))) uint32_t*)l, 16, 0, 0);
}

// ---------- NT GEMM: C[M,N] = A[M,K] @ B[N,K]^T ----------
// MODE 0: C stored as bf16 (y intermediate). MODE 1: C = acc + bias, fp32 store.
template <int MODE>
__global__ __launch_bounds__(256)
void gemm_nt(const unsigned short* __restrict__ A, const unsigned short* __restrict__ B,
             int K, int N,
             unsigned short* __restrict__ Cb, float* __restrict__ Cf,
             const float* __restrict__ bias) {
    __shared__ unsigned short ldsA[BM * BK];   // 8 KiB
    __shared__ unsigned short ldsB[BN * BK];   // 8 KiB

    const int tid  = threadIdx.x;
    const int wave = tid >> 6, lane = tid & 63;
    const int wm = wave >> 1, wn = wave & 1;       // 2x2 waves -> 64x64 each
    const int q = lane >> 4, l16 = lane & 15;
    const int m0 = blockIdx.y * BM, n0 = blockIdx.x * BN;

    f32x4 acc[4][4] = {};

    // staging: 512 chunks of 8 bf16 (16B); thread t owns chunks t and t+256.
    // LDS dest = chunk*16B (row-major [128][32], no padding — required by
    // global_load_lds wave-uniform-base + lane*16 semantics).
    const int rowc = tid >> 2;
    const int colc = (tid & 3) << 3;
    const unsigned short* gA0 = A + (size_t)(m0 + rowc) * K + colc;
    const unsigned short* gA1 = A + (size_t)(m0 + rowc + 64) * K + colc;
    const unsigned short* gB0 = B + (size_t)(n0 + rowc) * K + colc;
    const unsigned short* gB1 = B + (size_t)(n0 + rowc + 64) * K + colc;
    unsigned short* lA0 = ldsA + tid * 8;
    unsigned short* lA1 = ldsA + (tid + 256) * 8;
    unsigned short* lB0 = ldsB + tid * 8;
    unsigned short* lB1 = ldsB + (tid + 256) * 8;

    const int nKT = K / BK;
    for (int kt = 0; kt < nKT; ++kt) {
        const int k0 = kt * BK;
        stage16(gA0 + k0, lA0);
        stage16(gA1 + k0, lA1);
        stage16(gB0 + k0, lB0);
        stage16(gB1 + k0, lB1);
        asm volatile("s_waitcnt vmcnt(0)" ::: "memory");
        __syncthreads();

        bf16x8 af[4], bfr[4];
#pragma unroll
        for (int t = 0; t < 4; ++t) {
            af[t]  = *(const bf16x8*)(ldsA + (wm * 64 + t * 16 + l16) * BK + q * 8);
            bfr[t] = *(const bf16x8*)(ldsB + (wn * 64 + t * 16 + l16) * BK + q * 8);
        }
#pragma unroll
        for (int mt = 0; mt < 4; ++mt)
#pragma unroll
            for (int nt = 0; nt < 4; ++nt)
                acc[mt][nt] = __builtin_amdgcn_mfma_f32_16x16x32_bf16(
                    af[mt], bfr[nt], acc[mt][nt], 0, 0, 0);
        __syncthreads();
    }

    // epilogue: D mapping col=lane&15, row=(lane>>4)*4 + reg  [verified m89]
#pragma unroll
    for (int mt = 0; mt < 4; ++mt) {
#pragma unroll
        for (int nt = 0; nt < 4; ++nt) {
            const int col = n0 + wn * 64 + nt * 16 + l16;
            const int rbase = m0 + wm * 64 + mt * 16 + q * 4;
            float bv = (MODE == 1) ? bias[col] : 0.0f;
#pragma unroll
            for (int i = 0; i < 4; ++i) {
                const int row = rbase + i;
                float v = acc[mt][nt][i];
                if (MODE == 0)
                    Cb[(size_t)row * N + col] = f32_to_bf16(v);
                else
                    Cf[(size_t)row * N + col] = v + bv;
            }
        }
    }
}

extern "C" void kernel_launch(void* const* d_in, const int* in_sizes, int n_in,
                              void* d_out, int out_size, void* d_ws, size_t ws_size,
                              hipStream_t stream) {
    const float* x    = (const float*)d_in[0];
    const float* u_t  = (const float*)d_in[1];
    const float* u_d  = (const float*)d_in[2];
    const float* s    = (const float*)d_in[3];
    const float* v_t  = (const float*)d_in[4];
    const float* v_d  = (const float*)d_in[5];
    const float* bias = (const float*)d_in[6];
    float* out = (float*)d_out;

    const int M = 8192, IN = 4096, R = 1024, OUT = 4096;

    char* ws = (char*)d_ws;
    unsigned short* xb = (unsigned short*)ws;                          // 64 MiB
    unsigned short* Vb = (unsigned short*)(ws + (size_t)(64 << 20));   //  8 MiB
    unsigned short* Ub = (unsigned short*)(ws + (size_t)(72 << 20));   //  8 MiB
    unsigned short* Y  = (unsigned short*)(ws + (size_t)(80 << 20));   // 16 MiB

    // casts (independent, serialized on stream — each is tiny/mem-bound)
    {
        int n4 = M * IN / 4;
        cast_f32_bf16<<<(n4 + 255) / 256, 256, 0, stream>>>(x, xb, n4);
    }
    {
        int n4 = 64 * IN / 4;
        cast_f32_bf16<<<(n4 + 255) / 256, 256, 0, stream>>>(v_t, Vb, n4);
    }
    {
        int n4 = 960 * IN / 4;
        cast_f32_bf16<<<(n4 + 255) / 256, 256, 0, stream>>>(v_d, Vb + 64 * IN, n4);
    }
    {
        int n4 = OUT * R / 4;
        build_u<<<(n4 + 255) / 256, 256, 0, stream>>>(u_t, u_d, s, Ub, n4);
    }

    // GEMM A: y[M,R] = xb @ Vb^T   (K=IN)
    gemm_nt<0><<<dim3(R / BN, M / BM), 256, 0, stream>>>(xb, Vb, IN, R, Y, nullptr, nullptr);
    // GEMM B: out[M,OUT] = y @ Ub^T + bias   (K=R)
    gemm_nt<1><<<dim3(OUT / BN, M / BM), 256, 0, stream>>>(Y, Ub, R, OUT, nullptr, out, bias);
}